// Round 1
// baseline (109.329 us; speedup 1.0000x reference)
//
#include <hip/hip_runtime.h>

#define TLEN 600
#define PLEN 144
#define KW   25
#define PADW 12   // KW/2

// One block per row (row = one [b, c, n] slice, 600 contiguous floats).
// Row is staged in LDS with zero pads; trend = 25-tap mean (count_include_pad),
// daily[t] = mean over the 4 full periods of phase (t % 144), for all t
// (tail positions 576..599 reduce to phases 0..23 identically).
__global__ __launch_bounds__(256) void decomp_kernel(
    const float* __restrict__ x,
    float* __restrict__ hf,
    float* __restrict__ daily,
    float* __restrict__ trend,
    int nrows)
{
    __shared__ float s[TLEN + 2 * PADW];  // 624 floats, zero-padded row
    __shared__ float mk[PLEN];            // per-phase means

    int row = blockIdx.x;
    if (row >= nrows) return;

    const float* xr = x + (size_t)row * TLEN;

    // --- stage row into LDS, vectorized float4 (600 = 150 * 4) ---
    const float4* xr4 = (const float4*)xr;
    for (int i = threadIdx.x; i < TLEN / 4; i += blockDim.x) {
        float4 v = xr4[i];
        int base = PADW + i * 4;
        s[base + 0] = v.x;
        s[base + 1] = v.y;
        s[base + 2] = v.z;
        s[base + 3] = v.w;
    }
    if (threadIdx.x < PADW) {
        s[threadIdx.x] = 0.0f;                  // left pad
        s[TLEN + PADW + threadIdx.x] = 0.0f;    // right pad
    }
    __syncthreads();

    // --- per-phase means over the 4 full periods (576 = 4 * 144) ---
    if (threadIdx.x < PLEN) {
        int p = threadIdx.x;
        mk[p] = 0.25f * (s[PADW + p] + s[PADW + p + 144] +
                         s[PADW + p + 288] + s[PADW + p + 432]);
    }
    __syncthreads();

    size_t ob = (size_t)row * TLEN;
    for (int t = threadIdx.x; t < TLEN; t += blockDim.x) {
        // 25-tap window sum; s[] is zero-padded so no branches.
        // Lane i reads s[t+j]: consecutive lanes -> consecutive banks, conflict-free.
        float sum = 0.0f;
#pragma unroll
        for (int j = 0; j < KW; ++j) sum += s[t + j];
        float tr = sum * (1.0f / (float)KW);

        float d = mk[t % PLEN];
        float low = 0.5f * (tr + d);

        hf[ob + t]    = s[PADW + t] - low;
        daily[ob + t] = d;
        trend[ob + t] = tr;
    }
}

extern "C" void kernel_launch(void* const* d_in, const int* in_sizes, int n_in,
                              void* d_out, int out_size, void* d_ws, size_t ws_size,
                              hipStream_t stream) {
    const float* x = (const float*)d_in[0];
    int total = in_sizes[0];          // 8*32*207*600
    int nrows = total / TLEN;         // 52992

    float* out   = (float*)d_out;
    float* hf    = out;                       // output 0
    float* daily = out + (size_t)total;       // output 1
    float* trend = out + 2 * (size_t)total;   // output 2

    decomp_kernel<<<nrows, 256, 0, stream>>>(x, hf, daily, trend, nrows);
}

// Round 2
// 92.526 us; speedup vs baseline: 1.1816x; 1.1816x over previous
//
#include <hip/hip_runtime.h>

#define TLEN 600
#define PLEN 144
#define KW   25
#define PADW 12            // KW/2; 12 floats = 3 float4 = 48 B (16B aligned)
#define SROW (TLEN + 2*PADW)   // 624
#define NC   (TLEN/4)      // 150 float4-chunks per row
#define RPB  2             // rows per block
#define NTHREADS 320       // 5 waves; 300 work items -> one full-width pass

// One block = 2 rows. Row staged zero-padded in LDS. Each thread computes 4
// consecutive outputs: the 4 overlapping 25-tap windows span s[4i..4i+27]
// = exactly 7 ds_read_b128; v3 of that load IS x[4i..4i+3] (PADW==12).
// daily[t] = mk[t % 144] (576 = 4*144, tail 24 wraps to phases 0..23).
__global__ __launch_bounds__(NTHREADS) void decomp_kernel(
    const float* __restrict__ x,
    float* __restrict__ hf,
    float* __restrict__ daily,
    float* __restrict__ trend)
{
    __shared__ float s[RPB][SROW];
    __shared__ float mk[RPB][PLEN];

    const int tid = threadIdx.x;
    const size_t row0 = (size_t)blockIdx.x * RPB;

    // --- stage 2 rows, one float4 per lane (300 of 320 lanes) ---
    if (tid < RPB * NC) {
        int r = tid >= NC;           // RPB == 2
        int i = tid - r * NC;
        float4 v = ((const float4*)(x + (row0 + r) * TLEN))[i];
        *(float4*)&s[r][PADW + 4 * i] = v;   // byte off 48 + 16i: aligned
    }
    // --- zero the 12-float pads (48 lanes) ---
    if (tid < RPB * 2 * PADW) {
        int r = tid / (2 * PADW);
        int k = tid - r * (2 * PADW);
        int idx = (k < PADW) ? k : (SROW - 2 * PADW + k);  // 0..11 | 612..623
        s[r][idx] = 0.0f;
    }
    __syncthreads();

    // --- per-phase means over 4 full periods (288 lanes) ---
    if (tid < RPB * PLEN) {
        int r = tid >= PLEN;
        int p = tid - r * PLEN;
        const float* sp = &s[r][PADW + p];
        mk[r][p] = 0.25f * (sp[0] + sp[144] + sp[288] + sp[432]);
    }
    __syncthreads();

    // --- compute + store: one 4-wide chunk per lane ---
    if (tid < RPB * NC) {
        int r = tid >= NC;
        int i = tid - r * NC;

        const float4* w = (const float4*)&s[r][4 * i];  // 16B aligned
        float4 v0 = w[0], v1 = w[1], v2 = w[2], v3 = w[3];
        float4 v4 = w[4], v5 = w[5], v6 = w[6];

        float w0 = ((v0.x + v0.y) + (v0.z + v0.w))
                 + ((v1.x + v1.y) + (v1.z + v1.w))
                 + ((v2.x + v2.y) + (v2.z + v2.w))
                 + ((v3.x + v3.y) + (v3.z + v3.w))
                 + ((v4.x + v4.y) + (v4.z + v4.w))
                 + ((v5.x + v5.y) + (v5.z + v5.w))
                 + v6.x;
        float w1 = w0 - v0.x + v6.y;
        float w2 = w1 - v0.y + v6.z;
        float w3 = w2 - v0.z + v6.w;

        const float inv = 1.0f / (float)KW;
        float4 tr = make_float4(w0 * inv, w1 * inv, w2 * inv, w3 * inv);

        int p4 = (i % 36) * 4;                       // phase block, aligned
        float4 d = *(const float4*)&mk[r][p4];

        float4 h;                                    // v3 == x[4i..4i+3]
        h.x = v3.x - 0.5f * (tr.x + d.x);
        h.y = v3.y - 0.5f * (tr.y + d.y);
        h.z = v3.z - 0.5f * (tr.z + d.z);
        h.w = v3.w - 0.5f * (tr.w + d.w);

        size_t ob = (row0 + r) * TLEN + 4 * i;
        *(float4*)(hf + ob)    = h;
        *(float4*)(daily + ob) = d;
        *(float4*)(trend + ob) = tr;
    }
}

extern "C" void kernel_launch(void* const* d_in, const int* in_sizes, int n_in,
                              void* d_out, int out_size, void* d_ws, size_t ws_size,
                              hipStream_t stream) {
    const float* x = (const float*)d_in[0];
    int total = in_sizes[0];           // 8*32*207*600 = 31,795,200
    int nrows = total / TLEN;          // 52,992 (even)

    float* out   = (float*)d_out;
    float* hf    = out;
    float* daily = out + (size_t)total;
    float* trend = out + 2 * (size_t)total;

    decomp_kernel<<<nrows / RPB, NTHREADS, 0, stream>>>(x, hf, daily, trend);
}